// Round 1
// baseline (624.909 us; speedup 1.0000x reference)
//
#include <hip/hip_runtime.h>
#include <hip/hip_bf16.h>

// B=2, L=4096, D=1024, E=3072, FW=64. Only streams 0 and 2 of the expansion
// are ever used by the reference recurrence; stream 1 is skipped entirely.

typedef __bf16 bf16x8 __attribute__((ext_vector_type(8)));
typedef float  f32x4  __attribute__((ext_vector_type(4)));

// XOR chunk-swizzle for the FIR LDS row: lanes read 32-float windows at a
// 16-float (64B) lane stride -> unswizzled this is an 8-way bank conflict.
// Swizzling the 4-float chunk index (low 3 bits ^ bits [5:3]) is bijective
// and spreads each 8-lane phase group across all 32 banks.
__device__ __forceinline__ int swz(int i) {
    int q = i >> 2;
    q ^= (q >> 3) & 7;
    return (q << 2) | (i & 3);
}

__device__ __forceinline__ float silu(float x) { return x / (1.f + __expf(-x)); }

// ---------------- K0: filter taps h[j] = filters[0, j] ----------------
// t[0] == 0 exactly => pos@w1 == 0, exp factor == 1. Fully general in b1/b2/w2/w3.
__global__ __launch_bounds__(256) void hgen(const float* __restrict__ b1,
                                            const float* __restrict__ w2,
                                            const float* __restrict__ b2,
                                            const float* __restrict__ w3,
                                            float* __restrict__ h) {
    __shared__ float hm2[64];
    int t = threadIdx.x;
    if (t < 64) {
        float acc = b2[t];
        for (int f = 0; f < 64; ++f) acc += silu(b1[f]) * w2[f * 64 + t];
        hm2[t] = silu(acc);
    }
    __syncthreads();
    for (int r = 0; r < 4; ++r) {
        int j = t * 4 + r;   // 0..1023
        float acc = 0.f;
        for (int g = 0; g < 64; ++g) acc += hm2[g] * w3[g * 1024 + j];
        h[j] = acc;
    }
}

// ---------------- K1: u = x @ w_in + b_in (columns 0..1023 and 2048..3071) ----
// 64x64 tile, 4 waves, each wave 16(M)x64(N) via 4x mfma_f32_16x16x32_bf16.
__global__ __launch_bounds__(256) void gemm1(const float* __restrict__ x,
                                             const float* __restrict__ w_in,
                                             const float* __restrict__ b_in,
                                             __bf16* __restrict__ u0,
                                             __bf16* __restrict__ u2) {
    __shared__ __bf16 As[64 * 40];   // [row][k], stride 40 (80B) -> conflict-free b128
    __shared__ __bf16 Bs[64 * 40];   // transposed: [n][k], stride 40
    int t  = threadIdx.x;
    int m0 = blockIdx.x * 64;
    int nt = blockIdx.y;
    int e_base = (nt < 16) ? nt * 64 : 2048 + (nt - 16) * 64;
    __bf16* uo = (nt < 16) ? u0 : u2;
    int outcol = (nt & 15) * 64;

    f32x4 acc[4] = {};
    int arow = t >> 2, aq = t & 3;   // A stage: 64 rows x 4 quads of 8
    int brow = t >> 3, bq = t & 7;   // B stage: 32 k-rows x 8 n-groups of 8

    for (int kk = 0; kk < 1024; kk += 32) {
        {   // stage A: x[m0+arow][kk + aq*8 .. +7]  f32 -> bf16
            const float* p = x + (size_t)(m0 + arow) * 1024 + kk + aq * 8;
            f32x4 a0 = *(const f32x4*)p;
            f32x4 a1 = *(const f32x4*)(p + 4);
            bf16x8 v;
            v[0] = (__bf16)a0[0]; v[1] = (__bf16)a0[1]; v[2] = (__bf16)a0[2]; v[3] = (__bf16)a0[3];
            v[4] = (__bf16)a1[0]; v[5] = (__bf16)a1[1]; v[6] = (__bf16)a1[2]; v[7] = (__bf16)a1[3];
            *(bf16x8*)&As[arow * 40 + aq * 8] = v;
        }
        {   // stage B transposed: w_in[kk+brow][e_base + bq*8 .. +7]
            const float* p = w_in + (size_t)(kk + brow) * 3072 + e_base + bq * 8;
            f32x4 b0 = *(const f32x4*)p;
            f32x4 b1v = *(const f32x4*)(p + 4);
            #pragma unroll
            for (int i = 0; i < 8; ++i) {
                float f = (i < 4) ? b0[i] : b1v[i - 4];
                Bs[(bq * 8 + i) * 40 + brow] = (__bf16)f;
            }
        }
        __syncthreads();
        int lane = t & 63, w = t >> 6;
        bf16x8 af = *(const bf16x8*)&As[(w * 16 + (lane & 15)) * 40 + ((lane >> 4) << 3)];
        #pragma unroll
        for (int s = 0; s < 4; ++s) {
            bf16x8 bf = *(const bf16x8*)&Bs[(s * 16 + (lane & 15)) * 40 + ((lane >> 4) << 3)];
            acc[s] = __builtin_amdgcn_mfma_f32_16x16x32_bf16(af, bf, acc[s], 0, 0, 0);
        }
        __syncthreads();
    }
    int lane = t & 63, w = t >> 6;
    int rbase = m0 + w * 16 + ((lane >> 4) << 2);   // C/D: row=(lane>>4)*4+j, col=lane&15
    int cb = lane & 15;
    #pragma unroll
    for (int s = 0; s < 4; ++s) {
        float bias = b_in[e_base + s * 16 + cb];
        #pragma unroll
        for (int j = 0; j < 4; ++j)
            uo[(size_t)(rbase + j) * 1024 + outcol + s * 16 + cb] = (__bf16)(acc[s][j] + bias);
    }
}

// ---------------- K2: depthwise conv + gating + transpose to [B,D,L] ----------
// s0 = conv(u0-chan), s2 = conv(u2-chan); v = s0*s2. Writes v and s0 in [B,D,L] bf16.
__global__ __launch_bounds__(256) void convmul(const __bf16* __restrict__ u0,
                                               const __bf16* __restrict__ u2,
                                               const float* __restrict__ w_conv,
                                               const float* __restrict__ b_conv,
                                               __bf16* __restrict__ v,
                                               __bf16* __restrict__ s0out) {
    __shared__ float vt[64][65];
    __shared__ float st[64][65];
    int t = threadIdx.x;
    int b = blockIdx.z;
    int l0b = blockIdx.x * 64;
    int d0 = blockIdx.y * 64;
    int d = t & 63, lg = t >> 6;
    int col = d0 + d;
    int l0 = l0b + lg * 16;

    float c00 = w_conv[col * 3 + 0], c01 = w_conv[col * 3 + 1], c02 = w_conv[col * 3 + 2];
    float bc0 = b_conv[col];
    int e2 = 2048 + col;
    float c20 = w_conv[e2 * 3 + 0], c21 = w_conv[e2 * 3 + 1], c22 = w_conv[e2 * 3 + 2];
    float bc2 = b_conv[e2];

    size_t base = ((size_t)b * 4096 + l0) * 1024 + col;
    float p01 = (l0 >= 1) ? (float)u0[base - 1024] : 0.f;
    float p02 = (l0 >= 2) ? (float)u0[base - 2048] : 0.f;
    float p21 = (l0 >= 1) ? (float)u2[base - 1024] : 0.f;
    float p22 = (l0 >= 2) ? (float)u2[base - 2048] : 0.f;
    #pragma unroll
    for (int il = 0; il < 16; ++il) {
        float c0v = (float)u0[base + (size_t)il * 1024];
        float c2v = (float)u2[base + (size_t)il * 1024];
        float s0v = c00 * p02 + c01 * p01 + c02 * c0v + bc0;
        float s2v = c20 * p22 + c21 * p21 + c22 * c2v + bc2;
        p02 = p01; p01 = c0v; p22 = p21; p21 = c2v;
        vt[lg * 16 + il][d] = s0v * s2v;
        st[lg * 16 + il][d] = s0v;
    }
    __syncthreads();
    int lo = t & 63, dg = t >> 6;
    size_t obase = ((size_t)b * 1024 + d0 + dg * 16) * 4096 + l0b + lo;
    #pragma unroll
    for (int id = 0; id < 16; ++id) {
        v[obase + (size_t)id * 4096]     = (__bf16)vt[lo][dg * 16 + id];
        s0out[obase + (size_t)id * 4096] = (__bf16)st[lo][dg * 16 + id];
    }
}

// ---------------- K3: 1024-tap causal FIR per (b,d) row + bias + gate ---------
// y[l] = sum_j h[j]*v[l-j];  z = (y + v*filt_bias[d]) * s0   (all along L=4096)
__global__ __launch_bounds__(256) void firk(const __bf16* __restrict__ v,
                                            const __bf16* __restrict__ s0,
                                            const float* __restrict__ hg,
                                            const float* __restrict__ filt_bias,
                                            __bf16* __restrict__ z) {
    __shared__ float vp[5120];   // [0,1024)=zeros, [1024,5120)=v row (swizzled)
    __shared__ float hl[1024];
    int t = threadIdx.x;
    int bd = blockIdx.x;          // b*1024 + d
    int d = bd & 1023;
    const __bf16* vrow = v + (size_t)bd * 4096;

    #pragma unroll
    for (int c = 0; c < 4; ++c) vp[swz(t * 4 + c)] = 0.f;
    #pragma unroll
    for (int c = 0; c < 2; ++c) {
        bf16x8 v8 = *(const bf16x8*)&vrow[t * 16 + c * 8];
        #pragma unroll
        for (int k = 0; k < 8; ++k) vp[swz(1024 + t * 16 + c * 8 + k)] = (float)v8[k];
    }
    #pragma unroll
    for (int c = 0; c < 4; ++c) hl[t * 4 + c] = hg[t * 4 + c];
    __syncthreads();

    float acc[16] = {};
    for (int jb = 0; jb < 64; ++jb) {      // 16 taps per block
        int jb16 = jb << 4;
        f32x4 hh[4];
        #pragma unroll
        for (int q = 0; q < 4; ++q) hh[q] = *(const f32x4*)&hl[jb16 + 4 * q];
        int Lb = 1024 + (t << 4) - jb16 - 16;   // 16-aligned window base
        f32x4 wv[8];
        #pragma unroll
        for (int c = 0; c < 8; ++c) {
            int Lc = Lb + 4 * c;
            wv[c] = *(const f32x4*)&vp[swz(Lc)];
        }
        #pragma unroll
        for (int jj = 0; jj < 16; ++jj) {
            float hv = hh[jj >> 2][jj & 3];
            #pragma unroll
            for (int il = 0; il < 16; ++il) {
                int wi = 16 + il - jj;          // in [1,31], static after unroll
                acc[il] += hv * wv[wi >> 2][wi & 3];
            }
        }
    }

    float fb = filt_bias[d];
    const __bf16* s0row = s0 + (size_t)bd * 4096;
    __bf16* zrow = z + (size_t)bd * 4096;
    int l0 = t * 16;
    #pragma unroll
    for (int c = 0; c < 4; ++c) {
        f32x4 vv = *(const f32x4*)&vp[swz(1024 + l0 + 4 * c)];
        #pragma unroll
        for (int k = 0; k < 4; ++k) {
            int il = 4 * c + k;
            float sv = (float)s0row[l0 + il];
            zrow[l0 + il] = (__bf16)((acc[il] + vv[k] * fb) * sv);
        }
    }
}

// ---------------- K4: out = z @ w_out + b_out  (A staged from [B,D,L]) --------
__global__ __launch_bounds__(256) void gemm2(const __bf16* __restrict__ z,
                                             const float* __restrict__ w_out,
                                             const float* __restrict__ b_out,
                                             float* __restrict__ out) {
    __shared__ __bf16 As[64 * 40];
    __shared__ __bf16 Bs[64 * 40];
    int t = threadIdx.x;
    int m0 = blockIdx.x * 64;          // over B*L = 8192 (tiles never straddle b)
    int b  = m0 >> 12;
    int l0 = m0 & 4095;
    int n0 = blockIdx.y * 64;
    f32x4 acc[4] = {};
    int drow = t >> 3, lq = t & 7;     // A stage: 32 d-rows x 8 l-groups of 8
    int brow = t >> 3, bq = t & 7;

    for (int kk = 0; kk < 1024; kk += 32) {
        {   // A: z[b, kk+drow, l0 + lq*8 .. +7] -> As[l][d] (transpose)
            const __bf16* p = z + (size_t)(b * 1024 + kk + drow) * 4096 + l0 + lq * 8;
            bf16x8 v = *(const bf16x8*)p;
            #pragma unroll
            for (int i = 0; i < 8; ++i) As[(lq * 8 + i) * 40 + drow] = v[i];
        }
        {   // B transposed: w_out[kk+brow][n0 + bq*8 .. +7]
            const float* p = w_out + (size_t)(kk + brow) * 1024 + n0 + bq * 8;
            f32x4 b0 = *(const f32x4*)p;
            f32x4 b1v = *(const f32x4*)(p + 4);
            #pragma unroll
            for (int i = 0; i < 8; ++i) {
                float f = (i < 4) ? b0[i] : b1v[i - 4];
                Bs[(bq * 8 + i) * 40 + brow] = (__bf16)f;
            }
        }
        __syncthreads();
        int lane = t & 63, w = t >> 6;
        bf16x8 af = *(const bf16x8*)&As[(w * 16 + (lane & 15)) * 40 + ((lane >> 4) << 3)];
        #pragma unroll
        for (int s = 0; s < 4; ++s) {
            bf16x8 bf = *(const bf16x8*)&Bs[(s * 16 + (lane & 15)) * 40 + ((lane >> 4) << 3)];
            acc[s] = __builtin_amdgcn_mfma_f32_16x16x32_bf16(af, bf, acc[s], 0, 0, 0);
        }
        __syncthreads();
    }
    int lane = t & 63, w = t >> 6;
    int rbase = m0 + w * 16 + ((lane >> 4) << 2);
    int cb = lane & 15;
    #pragma unroll
    for (int s = 0; s < 4; ++s) {
        float bias = b_out[n0 + s * 16 + cb];
        #pragma unroll
        for (int j = 0; j < 4; ++j)
            out[(size_t)(rbase + j) * 1024 + n0 + s * 16 + cb] = acc[s][j] + bias;
    }
}

extern "C" void kernel_launch(void* const* d_in, const int* in_sizes, int n_in,
                              void* d_out, int out_size, void* d_ws, size_t ws_size,
                              hipStream_t stream) {
    const float* x      = (const float*)d_in[0];
    const float* w_in   = (const float*)d_in[1];
    const float* b_in   = (const float*)d_in[2];
    const float* w_conv = (const float*)d_in[3];
    const float* b_conv = (const float*)d_in[4];
    // d_in[5] = w1: multiplied by t[0]==0, mathematically unused for h
    const float* b1     = (const float*)d_in[6];
    const float* w2     = (const float*)d_in[7];
    const float* b2     = (const float*)d_in[8];
    const float* w3     = (const float*)d_in[9];
    const float* fb     = (const float*)d_in[10];
    const float* w_out  = (const float*)d_in[11];
    const float* b_out  = (const float*)d_in[12];
    float* out = (float*)d_out;

    // Workspace layout (bf16 intermediates): ~64 MB total
    char* ws = (char*)d_ws;
    float*  h  = (float*)ws;                          // 1024 f32 (4 KB)
    __bf16* u0 = (__bf16*)(ws + 4096);                // 8192x1024
    __bf16* u2 = u0 + (size_t)8192 * 1024;
    __bf16* vv = u2 + (size_t)8192 * 1024;            // [B,D,L]
    __bf16* ss = vv + (size_t)8192 * 1024;            // [B,D,L]
    __bf16* zz = u0;                                  // alias: u0 dead after convmul

    hgen<<<1, 256, 0, stream>>>(b1, w2, b2, w3, h);
    gemm1<<<dim3(128, 32), 256, 0, stream>>>(x, w_in, b_in, u0, u2);
    convmul<<<dim3(64, 16, 2), 256, 0, stream>>>(u0, u2, w_conv, b_conv, vv, ss);
    firk<<<2048, 256, 0, stream>>>(vv, ss, h, fb, zz);
    gemm2<<<dim3(128, 16), 256, 0, stream>>>(zz, w_out, b_out, out);
}

// Round 3
// 485.558 us; speedup vs baseline: 1.2870x; 1.2870x over previous
//
#include <hip/hip_runtime.h>
#include <hip/hip_bf16.h>

// B=2, L=4096, D=1024, E=3072, FW=64. Only streams 0 and 2 of the expansion
// are ever used by the reference recurrence; stream 1 is skipped entirely.

typedef __bf16 bf16x8 __attribute__((ext_vector_type(8)));
typedef float  f32x4  __attribute__((ext_vector_type(4)));

__device__ __forceinline__ float silu(float x) { return x / (1.f + __expf(-x)); }

// ---------------- K0: filter taps h[j] = filters[0, j] ----------------
// t[0] == 0 exactly => pos@w1 == 0, exp factor == 1. Fully general in b1/b2/w2/w3.
__global__ __launch_bounds__(256) void hgen(const float* __restrict__ b1,
                                            const float* __restrict__ w2,
                                            const float* __restrict__ b2,
                                            const float* __restrict__ w3,
                                            float* __restrict__ h) {
    __shared__ float hm2[64];
    int t = threadIdx.x;
    if (t < 64) {
        float acc = b2[t];
        for (int f = 0; f < 64; ++f) acc += silu(b1[f]) * w2[f * 64 + t];
        hm2[t] = silu(acc);
    }
    __syncthreads();
    for (int r = 0; r < 4; ++r) {
        int j = t * 4 + r;   // 0..1023
        float acc = 0.f;
        for (int g = 0; g < 64; ++g) acc += hm2[g] * w3[g * 1024 + j];
        h[j] = acc;
    }
}

// ---------------- K0b: banded-Toeplitz filter blocks in MFMA A-fragment order -
// A_sp[m][k] = h[32sp + m - k]        (k < 16;  s = 2sp,   r = k)
//            = h[32sp + 32 + m - k]   (k >= 16; s = 2sp+1, r = k-16)
// Fragment order: lane l holds A[m = l&15][k = (l>>4)*8 + j], j = 0..7.
__global__ void hfrag(const float* __restrict__ h, __bf16* __restrict__ af) {
    int sp = blockIdx.x;      // 0..32
    int lane = threadIdx.x;   // 0..63
    int m = lane & 15, kh = lane >> 4;
    bf16x8 v;
    #pragma unroll
    for (int j = 0; j < 8; ++j) {
        int k = kh * 8 + j;
        int idx = (k < 16) ? (32 * sp + m - k) : (32 * sp + 32 + m - k);
        float val = (idx >= 0 && idx < 1024) ? h[idx] : 0.f;
        v[j] = (__bf16)val;
    }
    *(bf16x8*)&af[(size_t)(sp * 64 + lane) * 8] = v;
}

// ---------------- K1: u = x @ w_in + b_in (columns 0..1023 and 2048..3071) ----
// 64x64 tile, 4 waves, each wave 16(M)x64(N) via 4x mfma_f32_16x16x32_bf16.
__global__ __launch_bounds__(256) void gemm1(const float* __restrict__ x,
                                             const float* __restrict__ w_in,
                                             const float* __restrict__ b_in,
                                             __bf16* __restrict__ u0,
                                             __bf16* __restrict__ u2) {
    __shared__ __bf16 As[64 * 40];   // [row][k], stride 40 (80B) -> conflict-free b128
    __shared__ __bf16 Bs[64 * 40];   // transposed: [n][k], stride 40
    int t  = threadIdx.x;
    int m0 = blockIdx.x * 64;
    int nt = blockIdx.y;
    int e_base = (nt < 16) ? nt * 64 : 2048 + (nt - 16) * 64;
    __bf16* uo = (nt < 16) ? u0 : u2;
    int outcol = (nt & 15) * 64;

    f32x4 acc[4] = {};
    int arow = t >> 2, aq = t & 3;   // A stage: 64 rows x 4 quads of 8
    int brow = t >> 3, bq = t & 7;   // B stage: 32 k-rows x 8 n-groups of 8

    for (int kk = 0; kk < 1024; kk += 32) {
        {   // stage A: x[m0+arow][kk + aq*8 .. +7]  f32 -> bf16
            const float* p = x + (size_t)(m0 + arow) * 1024 + kk + aq * 8;
            f32x4 a0 = *(const f32x4*)p;
            f32x4 a1 = *(const f32x4*)(p + 4);
            bf16x8 v;
            v[0] = (__bf16)a0[0]; v[1] = (__bf16)a0[1]; v[2] = (__bf16)a0[2]; v[3] = (__bf16)a0[3];
            v[4] = (__bf16)a1[0]; v[5] = (__bf16)a1[1]; v[6] = (__bf16)a1[2]; v[7] = (__bf16)a1[3];
            *(bf16x8*)&As[arow * 40 + aq * 8] = v;
        }
        {   // stage B transposed: w_in[kk+brow][e_base + bq*8 .. +7]
            const float* p = w_in + (size_t)(kk + brow) * 3072 + e_base + bq * 8;
            f32x4 b0 = *(const f32x4*)p;
            f32x4 b1v = *(const f32x4*)(p + 4);
            #pragma unroll
            for (int i = 0; i < 8; ++i) {
                float f = (i < 4) ? b0[i] : b1v[i - 4];
                Bs[(bq * 8 + i) * 40 + brow] = (__bf16)f;
            }
        }
        __syncthreads();
        int lane = t & 63, w = t >> 6;
        bf16x8 af = *(const bf16x8*)&As[(w * 16 + (lane & 15)) * 40 + ((lane >> 4) << 3)];
        #pragma unroll
        for (int s = 0; s < 4; ++s) {
            bf16x8 bf = *(const bf16x8*)&Bs[(s * 16 + (lane & 15)) * 40 + ((lane >> 4) << 3)];
            acc[s] = __builtin_amdgcn_mfma_f32_16x16x32_bf16(af, bf, acc[s], 0, 0, 0);
        }
        __syncthreads();
    }
    int lane = t & 63, w = t >> 6;
    int rbase = m0 + w * 16 + ((lane >> 4) << 2);   // C/D: row=(lane>>4)*4+j, col=lane&15
    int cb = lane & 15;
    #pragma unroll
    for (int s = 0; s < 4; ++s) {
        float bias = b_in[e_base + s * 16 + cb];
        #pragma unroll
        for (int j = 0; j < 4; ++j)
            uo[(size_t)(rbase + j) * 1024 + outcol + s * 16 + cb] = (__bf16)(acc[s][j] + bias);
    }
}

// ---------------- K2: depthwise conv + gating + transpose to [B,D,L] ----------
// s0 = conv(u0-chan), s2 = conv(u2-chan); v = s0*s2. Writes v and s0 in [B,D,L] bf16.
__global__ __launch_bounds__(256) void convmul(const __bf16* __restrict__ u0,
                                               const __bf16* __restrict__ u2,
                                               const float* __restrict__ w_conv,
                                               const float* __restrict__ b_conv,
                                               __bf16* __restrict__ v,
                                               __bf16* __restrict__ s0out) {
    __shared__ float vt[64][65];
    __shared__ float st[64][65];
    int t = threadIdx.x;
    int b = blockIdx.z;
    int l0b = blockIdx.x * 64;
    int d0 = blockIdx.y * 64;
    int d = t & 63, lg = t >> 6;
    int col = d0 + d;
    int l0 = l0b + lg * 16;

    float c00 = w_conv[col * 3 + 0], c01 = w_conv[col * 3 + 1], c02 = w_conv[col * 3 + 2];
    float bc0 = b_conv[col];
    int e2 = 2048 + col;
    float c20 = w_conv[e2 * 3 + 0], c21 = w_conv[e2 * 3 + 1], c22 = w_conv[e2 * 3 + 2];
    float bc2 = b_conv[e2];

    size_t base = ((size_t)b * 4096 + l0) * 1024 + col;
    float p01 = (l0 >= 1) ? (float)u0[base - 1024] : 0.f;
    float p02 = (l0 >= 2) ? (float)u0[base - 2048] : 0.f;
    float p21 = (l0 >= 1) ? (float)u2[base - 1024] : 0.f;
    float p22 = (l0 >= 2) ? (float)u2[base - 2048] : 0.f;
    #pragma unroll
    for (int il = 0; il < 16; ++il) {
        float c0v = (float)u0[base + (size_t)il * 1024];
        float c2v = (float)u2[base + (size_t)il * 1024];
        float s0v = c00 * p02 + c01 * p01 + c02 * c0v + bc0;
        float s2v = c20 * p22 + c21 * p21 + c22 * c2v + bc2;
        p02 = p01; p01 = c0v; p22 = p21; p21 = c2v;
        vt[lg * 16 + il][d] = s0v * s2v;
        st[lg * 16 + il][d] = s0v;
    }
    __syncthreads();
    int lo = t & 63, dg = t >> 6;
    size_t obase = ((size_t)b * 1024 + d0 + dg * 16) * 4096 + l0b + lo;
    #pragma unroll
    for (int id = 0; id < 16; ++id) {
        v[obase + (size_t)id * 4096]     = (__bf16)vt[lo][dg * 16 + id];
        s0out[obase + (size_t)id * 4096] = (__bf16)st[lo][dg * 16 + id];
    }
}

// ---------------- K3: 1024-tap causal FIR via MFMA block-Toeplitz -------------
// y[16p+m] = sum_{s=0}^{64} sum_{r<16} h[16s+m-r] * v[16(p-s)+r]
// One block per (b,d) row. A-fragments (filter) staged from global (hfrag output),
// v row staged zero-padded into LDS with a bijective 16B-chunk XOR swizzle
// (c ^= (c>>3)&7) so the 32B lane stride of B-fragment reads is <=2-way per bank
// slot. Main loop: pure ds_read_b128 + MFMA, single barrier, no per-iter sync.
__global__ __launch_bounds__(256) void firk(const __bf16* __restrict__ v,
                                            const __bf16* __restrict__ s0,
                                            const __bf16* __restrict__ afg,
                                            const float* __restrict__ filt_bias,
                                            __bf16* __restrict__ z) {
    __shared__ __bf16 vlds[768 * 8];       // 12288 B: chunks 0..129 zero-pad, 130..641 data
    __shared__ __bf16 alds[33 * 64 * 8];   // 33792 B: A-fragments, lane-contiguous
    int t = threadIdx.x;
    int bd = blockIdx.x;          // b*1024 + d
    int d = bd & 1023;
    const __bf16* vrow = v + (size_t)bd * 4096;

    for (int c = t; c < 33 * 64; c += 256)
        *(bf16x8*)&alds[c * 8] = *(const bf16x8*)&afg[(size_t)c * 8];
    #pragma unroll
    for (int i = 0; i < 3; ++i) {
        int c = t + i * 256;
        bf16x8 val = {};
        if (c >= 130 && c < 642) val = *(const bf16x8*)&vrow[(c - 130) * 8];
        int cs = c ^ ((c >> 3) & 7);
        *(bf16x8*)&vlds[cs * 8] = val;
    }
    __syncthreads();

    int lane = t & 63, w = t >> 6;
    int n = lane & 15, kh = lane >> 4;
    int khoff = (kh == 0) ? 0 : (kh == 1) ? 8 : (kh == 2) ? -16 : -8;
    f32x4 acc[4] = {};
    for (int sp = 0; sp < 33; ++sp) {
        bf16x8 af = *(const bf16x8*)&alds[(sp * 64 + lane) * 8];
        #pragma unroll
        for (int ct = 0; ct < 4; ++ct) {
            int p = w * 64 + ct * 16 + n;
            int e = 16 * p - 32 * sp + 1040 + khoff;   // vpad index, multiple of 8
            int c = e >> 3;
            int cs = c ^ ((c >> 3) & 7);
            bf16x8 bfv = *(const bf16x8*)&vlds[cs * 8];
            acc[ct] = __builtin_amdgcn_mfma_f32_16x16x32_bf16(af, bfv, acc[ct], 0, 0, 0);
        }
    }

    float fb = filt_bias[d];
    const __bf16* s0row = s0 + (size_t)bd * 4096;
    __bf16* zrow = z + (size_t)bd * 4096;
    #pragma unroll
    for (int ct = 0; ct < 4; ++ct) {
        int p = w * 64 + ct * 16 + n;
        #pragma unroll
        for (int j = 0; j < 4; ++j) {
            int l = 16 * p + kh * 4 + j;               // C/D: row=(lane>>4)*4+j, col=lane&15
            int e = l + 1040;
            int c = e >> 3;
            int cs = c ^ ((c >> 3) & 7);
            float vv = (float)vlds[cs * 8 + (e & 7)];
            float sv = (float)s0row[l];
            zrow[l] = (__bf16)((acc[ct][j] + vv * fb) * sv);
        }
    }
}

// ---------------- K4: out = z @ w_out + b_out  (A staged from [B,D,L]) --------
__global__ __launch_bounds__(256) void gemm2(const __bf16* __restrict__ z,
                                             const float* __restrict__ w_out,
                                             const float* __restrict__ b_out,
                                             float* __restrict__ out) {
    __shared__ __bf16 As[64 * 40];
    __shared__ __bf16 Bs[64 * 40];
    int t = threadIdx.x;
    int m0 = blockIdx.x * 64;          // over B*L = 8192 (tiles never straddle b)
    int b  = m0 >> 12;
    int l0 = m0 & 4095;
    int n0 = blockIdx.y * 64;
    f32x4 acc[4] = {};
    int drow = t >> 3, lq = t & 7;     // A stage: 32 d-rows x 8 l-groups of 8
    int brow = t >> 3, bq = t & 7;

    for (int kk = 0; kk < 1024; kk += 32) {
        {   // A: z[b, kk+drow, l0 + lq*8 .. +7] -> As[l][d] (transpose)
            const __bf16* p = z + (size_t)(b * 1024 + kk + drow) * 4096 + l0 + lq * 8;
            bf16x8 v = *(const bf16x8*)p;
            #pragma unroll
            for (int i = 0; i < 8; ++i) As[(lq * 8 + i) * 40 + drow] = v[i];
        }
        {   // B transposed: w_out[kk+brow][n0 + bq*8 .. +7]
            const float* p = w_out + (size_t)(kk + brow) * 1024 + n0 + bq * 8;
            f32x4 b0 = *(const f32x4*)p;
            f32x4 b1v = *(const f32x4*)(p + 4);
            #pragma unroll
            for (int i = 0; i < 8; ++i) {
                float f = (i < 4) ? b0[i] : b1v[i - 4];
                Bs[(bq * 8 + i) * 40 + brow] = (__bf16)f;
            }
        }
        __syncthreads();
        int lane = t & 63, w = t >> 6;
        bf16x8 af = *(const bf16x8*)&As[(w * 16 + (lane & 15)) * 40 + ((lane >> 4) << 3)];
        #pragma unroll
        for (int s = 0; s < 4; ++s) {
            bf16x8 bf = *(const bf16x8*)&Bs[(s * 16 + (lane & 15)) * 40 + ((lane >> 4) << 3)];
            acc[s] = __builtin_amdgcn_mfma_f32_16x16x32_bf16(af, bf, acc[s], 0, 0, 0);
        }
        __syncthreads();
    }
    int lane = t & 63, w = t >> 6;
    int rbase = m0 + w * 16 + ((lane >> 4) << 2);
    int cb = lane & 15;
    #pragma unroll
    for (int s = 0; s < 4; ++s) {
        float bias = b_out[n0 + s * 16 + cb];
        #pragma unroll
        for (int j = 0; j < 4; ++j)
            out[(size_t)(rbase + j) * 1024 + n0 + s * 16 + cb] = acc[s][j] + bias;
    }
}

extern "C" void kernel_launch(void* const* d_in, const int* in_sizes, int n_in,
                              void* d_out, int out_size, void* d_ws, size_t ws_size,
                              hipStream_t stream) {
    const float* x      = (const float*)d_in[0];
    const float* w_in   = (const float*)d_in[1];
    const float* b_in   = (const float*)d_in[2];
    const float* w_conv = (const float*)d_in[3];
    const float* b_conv = (const float*)d_in[4];
    // d_in[5] = w1: multiplied by t[0]==0, mathematically unused for h
    const float* b1     = (const float*)d_in[6];
    const float* w2     = (const float*)d_in[7];
    const float* b2     = (const float*)d_in[8];
    const float* w3     = (const float*)d_in[9];
    const float* fb     = (const float*)d_in[10];
    const float* w_out  = (const float*)d_in[11];
    const float* b_out  = (const float*)d_in[12];
    float* out = (float*)d_out;

    // Workspace layout (bf16 intermediates): ~64 MB total
    char* ws = (char*)d_ws;
    float*  h  = (float*)ws;                          // 1024 f32 (4 KB)
    __bf16* af = (__bf16*)(ws + 4096);                // 33*64*8 bf16 = 33 KB (pad to 36 KB)
    __bf16* u0 = (__bf16*)(ws + 40960);               // 8192x1024
    __bf16* u2 = u0 + (size_t)8192 * 1024;
    __bf16* vv = u2 + (size_t)8192 * 1024;            // [B,D,L]
    __bf16* ss = vv + (size_t)8192 * 1024;            // [B,D,L]
    __bf16* zz = u0;                                  // alias: u0 dead after convmul

    hgen<<<1, 256, 0, stream>>>(b1, w2, b2, w3, h);
    hfrag<<<33, 64, 0, stream>>>(h, af);
    gemm1<<<dim3(128, 32), 256, 0, stream>>>(x, w_in, b_in, u0, u2);
    convmul<<<dim3(64, 16, 2), 256, 0, stream>>>(u0, u2, w_conv, b_conv, vv, ss);
    firk<<<2048, 256, 0, stream>>>(vv, ss, af, fb, zz);
    gemm2<<<dim3(128, 16), 256, 0, stream>>>(zz, w_out, b_out, out);
}

// Round 4
// 272.713 us; speedup vs baseline: 2.2915x; 1.7805x over previous
//
#include <hip/hip_runtime.h>
#include <hip/hip_bf16.h>

// B=2, L=4096, D=1024, E=3072, FW=64. Only streams 0 and 2 of the expansion
// are ever used by the reference recurrence; stream 1 is skipped entirely.

typedef __bf16 bf16x8 __attribute__((ext_vector_type(8)));
typedef float  f32x4  __attribute__((ext_vector_type(4)));

typedef const __attribute__((address_space(1))) unsigned int GU32;
typedef __attribute__((address_space(3))) unsigned int LU32;
#define GLL16(gp, lp) __builtin_amdgcn_global_load_lds((GU32*)(gp), (LU32*)(lp), 16, 0, 0)

__device__ __forceinline__ float silu(float x) { return x / (1.f + __expf(-x)); }

// ---------------- K0: filter taps h[j] = filters[0, j] ----------------
// t[0] == 0 exactly => pos@w1 == 0, exp factor == 1. Fully general in b1/b2/w2/w3.
__global__ __launch_bounds__(256) void hgen(const float* __restrict__ b1,
                                            const float* __restrict__ w2,
                                            const float* __restrict__ b2,
                                            const float* __restrict__ w3,
                                            float* __restrict__ h) {
    __shared__ float hm2[64];
    int t = threadIdx.x;
    if (t < 64) {
        float acc = b2[t];
        for (int f = 0; f < 64; ++f) acc += silu(b1[f]) * w2[f * 64 + t];
        hm2[t] = silu(acc);
    }
    __syncthreads();
    for (int r = 0; r < 4; ++r) {
        int j = t * 4 + r;   // 0..1023
        float acc = 0.f;
        for (int g = 0; g < 64; ++g) acc += hm2[g] * w3[g * 1024 + j];
        h[j] = acc;
    }
}

// ---------------- K0b: banded-Toeplitz filter blocks in MFMA A-fragment order -
// A_sp[m][k] = h[32sp + m - k]        (k < 16)
//            = h[32sp + 32 + m - k]   (k >= 16)
// Fragment order: lane l holds A[m = l&15][k = (l>>4)*8 + j], j = 0..7.
__global__ void hfrag(const float* __restrict__ h, __bf16* __restrict__ af) {
    int sp = blockIdx.x;      // 0..32
    int lane = threadIdx.x;   // 0..63
    int m = lane & 15, kh = lane >> 4;
    bf16x8 v;
    #pragma unroll
    for (int j = 0; j < 8; ++j) {
        int k = kh * 8 + j;
        int idx = (k < 16) ? (32 * sp + m - k) : (32 * sp + 32 + m - k);
        float val = (idx >= 0 && idx < 1024) ? h[idx] : 0.f;
        v[j] = (__bf16)val;
    }
    *(bf16x8*)&af[(size_t)(sp * 64 + lane) * 8] = v;
}

// ---------------- P0a: x f32 -> bf16 (vectorized elementwise) ----------------
__global__ __launch_bounds__(256) void cvt_x(const float* __restrict__ x,
                                             __bf16* __restrict__ xb) {
    size_t i = ((size_t)blockIdx.x * 256 + threadIdx.x) * 8;
    f32x4 a = *(const f32x4*)&x[i];
    f32x4 b = *(const f32x4*)&x[i + 4];
    bf16x8 v;
    v[0] = (__bf16)a[0]; v[1] = (__bf16)a[1]; v[2] = (__bf16)a[2]; v[3] = (__bf16)a[3];
    v[4] = (__bf16)b[0]; v[5] = (__bf16)b[1]; v[6] = (__bf16)b[2]; v[7] = (__bf16)b[3];
    *(bf16x8*)&xb[i] = v;
}

// ---------------- P0b: transpose+convert weight panel to [N][K] bf16 ----------
// dst[n0+nn][k0+r] = src[k0+r][cbase + n0 + nn]; 64x64 LDS tile, both sides coalesced.
__global__ __launch_bounds__(256) void tcvt(const float* __restrict__ src,
                                            __bf16* __restrict__ dst,
                                            int ld, int cbase) {
    __shared__ __bf16 tile[64][65];
    int t = threadIdx.x;
    int k0 = blockIdx.x * 64, n0 = blockIdx.y * 64;
    int c = t & 63, rg = t >> 6;
    #pragma unroll
    for (int i = 0; i < 16; ++i) {
        int r = rg * 16 + i;
        tile[r][c] = (__bf16)src[(size_t)(k0 + r) * ld + cbase + n0 + c];
    }
    __syncthreads();
    #pragma unroll
    for (int i = 0; i < 16; ++i) {
        int nn = rg * 16 + i;
        dst[(size_t)(n0 + nn) * 1024 + k0 + c] = tile[c][nn];
    }
}

// ---------------- m97-structure GEMM: C[M][N] = A[M][1024] @ Bt[N][1024]^T ----
// 128x128 tile, BK=32, 4 waves x (4x4) 16x16x32 fragments, global_load_lds 16B.
// EPI 0: dual bf16 outputs split at col 1024 (+b_in);  EPI 1: f32 out (+b_out).
template<int EPI>
__global__ __launch_bounds__(256) void gemm128(const __bf16* __restrict__ A,
                                               const __bf16* __restrict__ Bt,
                                               const float* __restrict__ bias,
                                               void* __restrict__ out0,
                                               void* __restrict__ out1) {
    __shared__ __bf16 As[128 * 32];   // [row][k] linear, 64B rows (global_load_lds dst)
    __shared__ __bf16 Bs[128 * 32];
    int t = threadIdx.x, lane = t & 63, w = t >> 6;
    int m0 = blockIdx.x * 128, n0 = blockIdx.y * 128;
    int wr = (w >> 1) * 64, wc = (w & 1) * 64;
    f32x4 acc[4][4] = {};

    int s1 = w * 64 + lane;          // 16B chunk ids: lds addr = wave_base + lane*16
    int s2 = s1 + 256;
    const __bf16* a1 = A + (size_t)(m0 + (s1 >> 2)) * 1024 + (s1 & 3) * 8;
    const __bf16* a2 = A + (size_t)(m0 + (s2 >> 2)) * 1024 + (s2 & 3) * 8;
    const __bf16* b1 = Bt + (size_t)(n0 + (s1 >> 2)) * 1024 + (s1 & 3) * 8;
    const __bf16* b2 = Bt + (size_t)(n0 + (s2 >> 2)) * 1024 + (s2 & 3) * 8;

    for (int kk = 0; kk < 1024; kk += 32) {
        GLL16(a1 + kk, &As[(size_t)s1 * 8]);
        GLL16(a2 + kk, &As[(size_t)s2 * 8]);
        GLL16(b1 + kk, &Bs[(size_t)s1 * 8]);
        GLL16(b2 + kk, &Bs[(size_t)s2 * 8]);
        __syncthreads();                      // compiler drains vmcnt before barrier
        int kh = (lane >> 4) * 8, rl = lane & 15;
        bf16x8 af[4], bf[4];
        #pragma unroll
        for (int i = 0; i < 4; ++i) {
            af[i] = *(const bf16x8*)&As[(wr + i * 16 + rl) * 32 + kh];
            bf[i] = *(const bf16x8*)&Bs[(wc + i * 16 + rl) * 32 + kh];
        }
        #pragma unroll
        for (int mi = 0; mi < 4; ++mi)
            #pragma unroll
            for (int ni = 0; ni < 4; ++ni)
                acc[mi][ni] = __builtin_amdgcn_mfma_f32_16x16x32_bf16(af[mi], bf[ni], acc[mi][ni], 0, 0, 0);
        __syncthreads();
    }

    int cb = lane & 15, rb = (lane >> 4) * 4;
    #pragma unroll
    for (int ni = 0; ni < 4; ++ni) {
        int col = n0 + wc + ni * 16 + cb;
        if (EPI == 0) {
            __bf16* uo = (col < 1024) ? (__bf16*)out0 : (__bf16*)out1;
            int oc = col & 1023;
            float bv = bias[(col < 1024) ? col : 1024 + col];   // E-col for stream 2
            #pragma unroll
            for (int mi = 0; mi < 4; ++mi) {
                int row = m0 + wr + mi * 16 + rb;
                #pragma unroll
                for (int j = 0; j < 4; ++j)
                    uo[(size_t)(row + j) * 1024 + oc] = (__bf16)(acc[mi][ni][j] + bv);
            }
        } else {
            float* o = (float*)out0;
            float bv = bias[col];
            #pragma unroll
            for (int mi = 0; mi < 4; ++mi) {
                int row = m0 + wr + mi * 16 + rb;
                #pragma unroll
                for (int j = 0; j < 4; ++j)
                    o[(size_t)(row + j) * 1024 + col] = acc[mi][ni][j] + bv;
            }
        }
    }
}

// ---------------- K2: depthwise conv + gating; v->[B,D,L], s0->[B,L,D] --------
__global__ __launch_bounds__(256) void convmul(const __bf16* __restrict__ u0,
                                               const __bf16* __restrict__ u2,
                                               const float* __restrict__ w_conv,
                                               const float* __restrict__ b_conv,
                                               __bf16* __restrict__ v,
                                               __bf16* __restrict__ st) {
    __shared__ float vt[64][65];
    int t = threadIdx.x;
    int b = blockIdx.z;
    int l0b = blockIdx.x * 64;
    int d0 = blockIdx.y * 64;
    int d = t & 63, lg = t >> 6;
    int col = d0 + d;
    int l0 = l0b + lg * 16;

    float c00 = w_conv[col * 3 + 0], c01 = w_conv[col * 3 + 1], c02 = w_conv[col * 3 + 2];
    float bc0 = b_conv[col];
    int e2 = 2048 + col;
    float c20 = w_conv[e2 * 3 + 0], c21 = w_conv[e2 * 3 + 1], c22 = w_conv[e2 * 3 + 2];
    float bc2 = b_conv[e2];

    size_t base = ((size_t)b * 4096 + l0) * 1024 + col;
    float p01 = (l0 >= 1) ? (float)u0[base - 1024] : 0.f;
    float p02 = (l0 >= 2) ? (float)u0[base - 2048] : 0.f;
    float p21 = (l0 >= 1) ? (float)u2[base - 1024] : 0.f;
    float p22 = (l0 >= 2) ? (float)u2[base - 2048] : 0.f;
    #pragma unroll
    for (int il = 0; il < 16; ++il) {
        float c0v = (float)u0[base + (size_t)il * 1024];
        float c2v = (float)u2[base + (size_t)il * 1024];
        float s0v = c00 * p02 + c01 * p01 + c02 * c0v + bc0;
        float s2v = c20 * p22 + c21 * p21 + c22 * c2v + bc2;
        p02 = p01; p01 = c0v; p22 = p21; p21 = c2v;
        vt[lg * 16 + il][d] = s0v * s2v;
        st[base + (size_t)il * 1024] = (__bf16)s0v;   // [B,L,D] direct, coalesced
    }
    __syncthreads();
    int lo = t & 63, dg = t >> 6;
    size_t obase = ((size_t)b * 1024 + d0 + dg * 16) * 4096 + l0b + lo;
    #pragma unroll
    for (int id = 0; id < 16; ++id)
        v[obase + (size_t)id * 4096] = (__bf16)vt[lo][dg * 16 + id];
}

// ---------------- K3: 1024-tap causal FIR via MFMA block-Toeplitz -------------
// zz[l] = y[l] + v[l]*fb  (gating by s0 deferred to trz). One block per (b,d) row.
__global__ __launch_bounds__(256) void firk(const __bf16* __restrict__ v,
                                            const __bf16* __restrict__ afg,
                                            const float* __restrict__ filt_bias,
                                            __bf16* __restrict__ z) {
    __shared__ __bf16 vlds[768 * 8];       // chunks 0..129 zero-pad, 130..641 data
    __shared__ __bf16 alds[33 * 64 * 8];   // A-fragments, lane-contiguous
    int t = threadIdx.x;
    int bd = blockIdx.x;          // b*1024 + d
    int d = bd & 1023;
    const __bf16* vrow = v + (size_t)bd * 4096;

    for (int c = t; c < 33 * 64; c += 256)
        *(bf16x8*)&alds[c * 8] = *(const bf16x8*)&afg[(size_t)c * 8];
    #pragma unroll
    for (int i = 0; i < 3; ++i) {
        int c = t + i * 256;
        bf16x8 val = {};
        if (c >= 130 && c < 642) val = *(const bf16x8*)&vrow[(c - 130) * 8];
        int cs = c ^ ((c >> 3) & 7);
        *(bf16x8*)&vlds[cs * 8] = val;
    }
    __syncthreads();

    int lane = t & 63, w = t >> 6;
    int n = lane & 15, kh = lane >> 4;
    int khoff = (kh == 0) ? 0 : (kh == 1) ? 8 : (kh == 2) ? -16 : -8;
    f32x4 acc[4] = {};
    for (int sp = 0; sp < 33; ++sp) {
        bf16x8 af = *(const bf16x8*)&alds[(sp * 64 + lane) * 8];
        #pragma unroll
        for (int ct = 0; ct < 4; ++ct) {
            int p = w * 64 + ct * 16 + n;
            int e = 16 * p - 32 * sp + 1040 + khoff;   // vpad index, multiple of 8
            int c = e >> 3;
            int cs = c ^ ((c >> 3) & 7);
            bf16x8 bfv = *(const bf16x8*)&vlds[cs * 8];
            acc[ct] = __builtin_amdgcn_mfma_f32_16x16x32_bf16(af, bfv, acc[ct], 0, 0, 0);
        }
    }

    float fb = filt_bias[d];
    __bf16* zrow = z + (size_t)bd * 4096;
    #pragma unroll
    for (int ct = 0; ct < 4; ++ct) {
        int p = w * 64 + ct * 16 + n;
        #pragma unroll
        for (int j = 0; j < 4; ++j) {
            int l = 16 * p + kh * 4 + j;               // C/D: row=(lane>>4)*4+j, col=lane&15
            int e = l + 1040;
            int c = e >> 3;
            int cs = c ^ ((c >> 3) & 7);
            float vv = (float)vlds[cs * 8 + (e & 7)];
            zrow[l] = (__bf16)(acc[ct][j] + vv * fb);
        }
    }
}

// ---------------- K3b: transpose zz [B,D,L] -> [B,L,D] and gate by s0 ---------
__global__ __launch_bounds__(256) void trz(const __bf16* __restrict__ zz,
                                           const __bf16* __restrict__ st,
                                           __bf16* __restrict__ zt) {
    __shared__ __bf16 tile[64][65];
    int t = threadIdx.x;
    int l0 = blockIdx.x * 64, d0 = blockIdx.y * 64, b = blockIdx.z;
    int c = t & 63, rg = t >> 6;
    #pragma unroll
    for (int i = 0; i < 16; ++i) {
        int r = rg * 16 + i;
        tile[r][c] = zz[((size_t)(b * 1024 + d0 + r)) * 4096 + l0 + c];
    }
    __syncthreads();
    #pragma unroll
    for (int i = 0; i < 16; ++i) {
        int li = rg * 16 + i;
        size_t o = ((size_t)b * 4096 + l0 + li) * 1024 + d0 + c;
        zt[o] = (__bf16)((float)tile[c][li] * (float)st[o]);
    }
}

extern "C" void kernel_launch(void* const* d_in, const int* in_sizes, int n_in,
                              void* d_out, int out_size, void* d_ws, size_t ws_size,
                              hipStream_t stream) {
    const float* x      = (const float*)d_in[0];
    const float* w_in   = (const float*)d_in[1];
    const float* b_in   = (const float*)d_in[2];
    const float* w_conv = (const float*)d_in[3];
    const float* b_conv = (const float*)d_in[4];
    // d_in[5] = w1: multiplied by t[0]==0, mathematically unused for h
    const float* b1     = (const float*)d_in[6];
    const float* w2     = (const float*)d_in[7];
    const float* b2     = (const float*)d_in[8];
    const float* w3     = (const float*)d_in[9];
    const float* fb     = (const float*)d_in[10];
    const float* w_out  = (const float*)d_in[11];
    const float* b_out  = (const float*)d_in[12];
    float* out = (float*)d_out;

    // Workspace span = 40960 + 64 MB, identical to the round-1-proven bound.
    // Regions (16 MB each, bf16 8192x1024) with temporal aliasing:
    //   X : xbf (P1) -> vv (P2-P3) -> wot (P5)
    //   U0: u0  (P1-P2) -> zt (P4-P5)
    //   U2: u2  (P1-P2) -> zz (P3-P4)
    //   ST: st  (P2...) ; wt overlaps ST's last 4MB (wt dead before st written)
    char* ws = (char*)d_ws;
    float*  h  = (float*)ws;                          // 4 KB
    __bf16* af = (__bf16*)(ws + 4096);                // 33 KB
    const size_t SEG = (size_t)8192 * 1024;
    __bf16* X  = (__bf16*)(ws + 40960);
    __bf16* U0 = X + SEG;
    __bf16* U2 = U0 + SEG;
    __bf16* ST = U2 + SEG;
    __bf16* WT = ST + SEG - (size_t)2048 * 1024;      // [2048][1024] bf16, 4 MB

    hgen<<<1, 256, 0, stream>>>(b1, w2, b2, w3, h);
    hfrag<<<33, 64, 0, stream>>>(h, af);
    cvt_x<<<4096, 256, 0, stream>>>(x, X);
    tcvt<<<dim3(16, 16), 256, 0, stream>>>(w_in, WT, 3072, 0);
    tcvt<<<dim3(16, 16), 256, 0, stream>>>(w_in, WT + (size_t)1024 * 1024, 3072, 2048);
    gemm128<0><<<dim3(64, 16), 256, 0, stream>>>(X, WT, b_in, U0, U2);
    convmul<<<dim3(64, 16, 2), 256, 0, stream>>>(U0, U2, w_conv, b_conv, X, ST);
    firk<<<2048, 256, 0, stream>>>(X, af, fb, U2);
    tcvt<<<dim3(16, 16), 256, 0, stream>>>(w_out, X, 1024, 0);   // wot into X (vv dead)
    trz<<<dim3(64, 16, 2), 256, 0, stream>>>(U2, ST, U0);
    gemm128<1><<<dim3(64, 8), 256, 0, stream>>>(U0, X, b_out, (void*)out, nullptr);
}

// Round 5
// 268.323 us; speedup vs baseline: 2.3289x; 1.0164x over previous
//
#include <hip/hip_runtime.h>
#include <hip/hip_bf16.h>

// B=2, L=4096, D=1024, E=3072, FW=64. Only streams 0 and 2 of the expansion
// are ever used by the reference recurrence; stream 1 is skipped entirely.

typedef __bf16 bf16x8 __attribute__((ext_vector_type(8)));
typedef float  f32x4  __attribute__((ext_vector_type(4)));

typedef const __attribute__((address_space(1))) unsigned int GU32;
typedef __attribute__((address_space(3))) unsigned int LU32;
#define GLL16(gp, lp) __builtin_amdgcn_global_load_lds((GU32*)(gp), (LU32*)(lp), 16, 0, 0)

#define CFENCE asm volatile("" ::: "memory")
#define SBAR   do { CFENCE; __builtin_amdgcn_s_barrier(); CFENCE; } while (0)
#define SCHEDB __builtin_amdgcn_sched_barrier(0)
#define VMCNT0 asm volatile("s_waitcnt vmcnt(0)" ::: "memory")

__device__ __forceinline__ float silu(float x) { return x / (1.f + __expf(-x)); }

// ---------------- K0: filter taps h[j] = filters[0, j] ----------------
// t[0] == 0 exactly => pos@w1 == 0, exp factor == 1. Fully general in b1/b2/w2/w3.
__global__ __launch_bounds__(256) void hgen(const float* __restrict__ b1,
                                            const float* __restrict__ w2,
                                            const float* __restrict__ b2,
                                            const float* __restrict__ w3,
                                            float* __restrict__ h) {
    __shared__ float hm2[64];
    int t = threadIdx.x;
    if (t < 64) {
        float acc = b2[t];
        for (int f = 0; f < 64; ++f) acc += silu(b1[f]) * w2[f * 64 + t];
        hm2[t] = silu(acc);
    }
    __syncthreads();
    for (int r = 0; r < 4; ++r) {
        int j = t * 4 + r;   // 0..1023
        float acc = 0.f;
        for (int g = 0; g < 64; ++g) acc += hm2[g] * w3[g * 1024 + j];
        h[j] = acc;
    }
}

// ---------------- K0b: banded-Toeplitz filter blocks in MFMA A-fragment order -
__global__ void hfrag(const float* __restrict__ h, __bf16* __restrict__ af) {
    int sp = blockIdx.x;      // 0..32
    int lane = threadIdx.x;   // 0..63
    int m = lane & 15, kh = lane >> 4;
    bf16x8 v;
    #pragma unroll
    for (int j = 0; j < 8; ++j) {
        int k = kh * 8 + j;
        int idx = (k < 16) ? (32 * sp + m - k) : (32 * sp + 32 + m - k);
        float val = (idx >= 0 && idx < 1024) ? h[idx] : 0.f;
        v[j] = (__bf16)val;
    }
    *(bf16x8*)&af[(size_t)(sp * 64 + lane) * 8] = v;
}

// ---------------- P0a: x f32 -> bf16 (vectorized elementwise) ----------------
__global__ __launch_bounds__(256) void cvt_x(const float* __restrict__ x,
                                             __bf16* __restrict__ xb) {
    size_t i = ((size_t)blockIdx.x * 256 + threadIdx.x) * 8;
    f32x4 a = *(const f32x4*)&x[i];
    f32x4 b = *(const f32x4*)&x[i + 4];
    bf16x8 v;
    v[0] = (__bf16)a[0]; v[1] = (__bf16)a[1]; v[2] = (__bf16)a[2]; v[3] = (__bf16)a[3];
    v[4] = (__bf16)b[0]; v[5] = (__bf16)b[1]; v[6] = (__bf16)b[2]; v[7] = (__bf16)b[3];
    *(bf16x8*)&xb[i] = v;
}

// ---------------- P0b: transpose+convert weight panel to [N][K] bf16 ----------
__global__ __launch_bounds__(256) void tcvt(const float* __restrict__ src,
                                            __bf16* __restrict__ dst,
                                            int ld, int cbase) {
    __shared__ __bf16 tile[64][65];
    int t = threadIdx.x;
    int k0 = blockIdx.x * 64, n0 = blockIdx.y * 64;
    int c = t & 63, rg = t >> 6;
    #pragma unroll
    for (int i = 0; i < 16; ++i) {
        int r = rg * 16 + i;
        tile[r][c] = (__bf16)src[(size_t)(k0 + r) * ld + cbase + n0 + c];
    }
    __syncthreads();
    #pragma unroll
    for (int i = 0; i < 16; ++i) {
        int nn = rg * 16 + i;
        dst[(size_t)(n0 + nn) * 1024 + k0 + c] = tile[c][nn];
    }
}

// ================= gemm256: 256x256-tile 8-phase GEMM (T2+T3+T4+T5) ===========
// C[M][N] = A[M][1024] @ Bt[N][1024]^T, bf16 in, dual-bf16 out split at col 1024.
// 512 threads = 8 waves (2M x 4N); per-wave C = 128x64. BK=64, 16 K-tiles.
// LDS 128KB = 2 dbuf x (A 2x16KB + B 2x16KB halves). During K-tile t the waves
// READ buf[t&1] and PREFETCH tile t+1 into buf[t&1 ^ 1] -- parities disjoint, so
// the only sync point is the tile boundary: per-wave vmcnt(0) (loads are ~2.5
// phases old there -> no stall) + barrier. st_16x32 swizzle both-sides:
// linear GLL dest + involutive source-chunk XOR (c ^= ((c>>5)&1)<<1) + read-side
// byte XOR (a ^= ((a>>9)&1)<<5).
__device__ __forceinline__ void stage_half(const __bf16* __restrict__ panel, int kk,
                                           char* ldshalf, int t) {
    int c1 = t, c2 = t + 512;
    int s1 = c1 ^ (((c1 >> 5) & 1) << 1);
    int s2 = c2 ^ (((c2 >> 5) & 1) << 1);
    GLL16(panel + (size_t)(s1 >> 3) * 1024 + kk + (s1 & 7) * 8, ldshalf + c1 * 16);
    GLL16(panel + (size_t)(s2 >> 3) * 1024 + kk + (s2 & 7) * 8, ldshalf + c2 * 16);
}

__global__ __launch_bounds__(512, 1) void gemm256(const __bf16* __restrict__ A,
                                                  const __bf16* __restrict__ Bt,
                                                  const float* __restrict__ bias,
                                                  __bf16* __restrict__ out0,
                                                  __bf16* __restrict__ out1) {
    __shared__ __bf16 lds[65536];          // 128 KB
    char* L = (char*)lds;
    int t = threadIdx.x, lane = t & 63, w = t >> 6;
    int wr = w >> 2, wc = w & 3;           // wave tile: rows wr*128, cols wc*64
    int m0 = blockIdx.x * 256, n0 = blockIdx.y * 256;
    int rl = lane & 15, kh8 = (lane >> 4) * 8;
    int nloc = (wc & 1) * 64;

    const __bf16* pa0 = A + (size_t)m0 * 1024;
    const __bf16* pa1 = A + (size_t)(m0 + 128) * 1024;
    const __bf16* pb0 = Bt + (size_t)n0 * 1024;
    const __bf16* pb1 = Bt + (size_t)(n0 + 128) * 1024;

    f32x4 acc[8][4] = {};
    bf16x8 ar[4][2], br[4][2];

#define RDA(dst, mf, ks) do { int _a = bA + ((mf) * 16 + rl) * 128 + ((ks) * 32 + kh8) * 2; \
        _a ^= ((_a >> 9) & 1) << 5; dst = *(const bf16x8*)(L + _a); } while (0)
#define RDB(dst, nf, ks) do { int _a = bB + (nloc + (nf) * 16 + rl) * 128 + ((ks) * 32 + kh8) * 2; \
        _a ^= ((_a >> 9) & 1) << 5; dst = *(const bf16x8*)(L + _a); } while (0)

    // prologue: stage K-tile 0 into buf 0
    stage_half(pa0, 0, L, t);
    stage_half(pa1, 0, L + 16384, t);
    stage_half(pb0, 0, L + 65536, t);
    stage_half(pb1, 0, L + 65536 + 16384, t);
    VMCNT0;
    SBAR;

    for (int kt = 0; kt < 16; ++kt) {
        int p = kt & 1, q = p ^ 1;
        int bA = p * 32768 + wr * 16384;
        int bB = 65536 + p * 32768 + (wc >> 1) * 16384;
        int kk1 = (kt + 1) * 64;

        // ---- phase 0: read A(mf 0-3) + B(nf 0-1); prefetch next A halves ----
        #pragma unroll
        for (int i = 0; i < 4; ++i) { RDA(ar[i][0], i, 0); RDA(ar[i][1], i, 1); }
        RDB(br[0][0], 0, 0); RDB(br[0][1], 0, 1);
        RDB(br[1][0], 1, 0); RDB(br[1][1], 1, 1);
        if (kt < 15) {
            stage_half(pa0, kk1, L + q * 32768, t);
            stage_half(pa1, kk1, L + q * 32768 + 16384, t);
        }
        SCHEDB; SBAR; SCHEDB;
        __builtin_amdgcn_s_setprio(1);
        #pragma unroll
        for (int mf = 0; mf < 4; ++mf)
            #pragma unroll
            for (int nf = 0; nf < 2; ++nf)
                #pragma unroll
                for (int ks = 0; ks < 2; ++ks)
                    acc[mf][nf] = __builtin_amdgcn_mfma_f32_16x16x32_bf16(ar[mf][ks], br[nf][ks], acc[mf][nf], 0, 0, 0);
        __builtin_amdgcn_s_setprio(0);
        SCHEDB; SBAR; SCHEDB;

        // ---- phase 1: read B(nf 2-3); prefetch next B halves ----
        RDB(br[2][0], 2, 0); RDB(br[2][1], 2, 1);
        RDB(br[3][0], 3, 0); RDB(br[3][1], 3, 1);
        if (kt < 15) {
            stage_half(pb0, kk1, L + 65536 + q * 32768, t);
            stage_half(pb1, kk1, L + 65536 + q * 32768 + 16384, t);
        }
        SCHEDB; SBAR; SCHEDB;
        __builtin_amdgcn_s_setprio(1);
        #pragma unroll
        for (int mf = 0; mf < 4; ++mf)
            #pragma unroll
            for (int nf = 2; nf < 4; ++nf)
                #pragma unroll
                for (int ks = 0; ks < 2; ++ks)
                    acc[mf][nf] = __builtin_amdgcn_mfma_f32_16x16x32_bf16(ar[mf][ks], br[nf][ks], acc[mf][nf], 0, 0, 0);
        __builtin_amdgcn_s_setprio(0);
        SCHEDB; SBAR; SCHEDB;

        // ---- phase 2: read A(mf 4-7) into ar ----
        #pragma unroll
        for (int i = 0; i < 4; ++i) { RDA(ar[i][0], 4 + i, 0); RDA(ar[i][1], 4 + i, 1); }
        SCHEDB; SBAR; SCHEDB;
        __builtin_amdgcn_s_setprio(1);
        #pragma unroll
        for (int mf = 0; mf < 4; ++mf)
            #pragma unroll
            for (int nf = 0; nf < 2; ++nf)
                #pragma unroll
                for (int ks = 0; ks < 2; ++ks)
                    acc[4 + mf][nf] = __builtin_amdgcn_mfma_f32_16x16x32_bf16(ar[mf][ks], br[nf][ks], acc[4 + mf][nf], 0, 0, 0);
        __builtin_amdgcn_s_setprio(0);
        SCHEDB; SBAR; SCHEDB;

        // ---- phase 3: MFMA only; boundary wait (own prefetches ~2.5 phases old) ----
        __builtin_amdgcn_s_setprio(1);
        #pragma unroll
        for (int mf = 0; mf < 4; ++mf)
            #pragma unroll
            for (int nf = 2; nf < 4; ++nf)
                #pragma unroll
                for (int ks = 0; ks < 2; ++ks)
                    acc[4 + mf][nf] = __builtin_amdgcn_mfma_f32_16x16x32_bf16(ar[mf][ks], br[nf][ks], acc[4 + mf][nf], 0, 0, 0);
        __builtin_amdgcn_s_setprio(0);
        VMCNT0;
        SCHEDB; SBAR; SCHEDB;
    }
#undef RDA
#undef RDB

    int cb = lane & 15, rb = (lane >> 4) * 4;
    #pragma unroll
    for (int nf = 0; nf < 4; ++nf) {
        int col = n0 + wc * 64 + nf * 16 + cb;
        __bf16* uo = (col < 1024) ? out0 : out1;
        int oc = col & 1023;
        float bv = bias[(col < 1024) ? col : 1024 + col];
        #pragma unroll
        for (int mf = 0; mf < 8; ++mf) {
            int row = m0 + wr * 128 + mf * 16 + rb;
            #pragma unroll
            for (int j = 0; j < 4; ++j)
                uo[(size_t)(row + j) * 1024 + oc] = (__bf16)(acc[mf][nf][j] + bv);
        }
    }
}

// ---------------- m97-structure 128x128 GEMM (kept for gemm2) -----------------
template<int EPI>
__global__ __launch_bounds__(256) void gemm128(const __bf16* __restrict__ A,
                                               const __bf16* __restrict__ Bt,
                                               const float* __restrict__ bias,
                                               void* __restrict__ out0,
                                               void* __restrict__ out1) {
    __shared__ __bf16 As[128 * 32];
    __shared__ __bf16 Bs[128 * 32];
    int t = threadIdx.x, lane = t & 63, w = t >> 6;
    int m0 = blockIdx.x * 128, n0 = blockIdx.y * 128;
    int wr = (w >> 1) * 64, wc = (w & 1) * 64;
    f32x4 acc[4][4] = {};

    int s1 = w * 64 + lane;
    int s2 = s1 + 256;
    const __bf16* a1 = A + (size_t)(m0 + (s1 >> 2)) * 1024 + (s1 & 3) * 8;
    const __bf16* a2 = A + (size_t)(m0 + (s2 >> 2)) * 1024 + (s2 & 3) * 8;
    const __bf16* b1 = Bt + (size_t)(n0 + (s1 >> 2)) * 1024 + (s1 & 3) * 8;
    const __bf16* b2 = Bt + (size_t)(n0 + (s2 >> 2)) * 1024 + (s2 & 3) * 8;

    for (int kk = 0; kk < 1024; kk += 32) {
        GLL16(a1 + kk, (char*)&As[(size_t)s1 * 8]);
        GLL16(a2 + kk, (char*)&As[(size_t)s2 * 8]);
        GLL16(b1 + kk, (char*)&Bs[(size_t)s1 * 8]);
        GLL16(b2 + kk, (char*)&Bs[(size_t)s2 * 8]);
        __syncthreads();
        int kh = (lane >> 4) * 8, rl = lane & 15;
        bf16x8 af[4], bf[4];
        #pragma unroll
        for (int i = 0; i < 4; ++i) {
            af[i] = *(const bf16x8*)&As[(wr + i * 16 + rl) * 32 + kh];
            bf[i] = *(const bf16x8*)&Bs[(wc + i * 16 + rl) * 32 + kh];
        }
        #pragma unroll
        for (int mi = 0; mi < 4; ++mi)
            #pragma unroll
            for (int ni = 0; ni < 4; ++ni)
                acc[mi][ni] = __builtin_amdgcn_mfma_f32_16x16x32_bf16(af[mi], bf[ni], acc[mi][ni], 0, 0, 0);
        __syncthreads();
    }

    int cb = lane & 15, rb = (lane >> 4) * 4;
    #pragma unroll
    for (int ni = 0; ni < 4; ++ni) {
        int col = n0 + wc + ni * 16 + cb;
        if (EPI == 0) {
            __bf16* uo = (col < 1024) ? (__bf16*)out0 : (__bf16*)out1;
            int oc = col & 1023;
            float bv = bias[(col < 1024) ? col : 1024 + col];
            #pragma unroll
            for (int mi = 0; mi < 4; ++mi) {
                int row = m0 + wr + mi * 16 + rb;
                #pragma unroll
                for (int j = 0; j < 4; ++j)
                    uo[(size_t)(row + j) * 1024 + oc] = (__bf16)(acc[mi][ni][j] + bv);
            }
        } else {
            float* o = (float*)out0;
            float bv = bias[col];
            #pragma unroll
            for (int mi = 0; mi < 4; ++mi) {
                int row = m0 + wr + mi * 16 + rb;
                #pragma unroll
                for (int j = 0; j < 4; ++j)
                    o[(size_t)(row + j) * 1024 + col] = acc[mi][ni][j] + bv;
            }
        }
    }
}

// ---------------- K2: depthwise conv + gating; v->[B,D,L], s0->[B,L,D] --------
__global__ __launch_bounds__(256) void convmul(const __bf16* __restrict__ u0,
                                               const __bf16* __restrict__ u2,
                                               const float* __restrict__ w_conv,
                                               const float* __restrict__ b_conv,
                                               __bf16* __restrict__ v,
                                               __bf16* __restrict__ st) {
    __shared__ float vt[64][65];
    int t = threadIdx.x;
    int b = blockIdx.z;
    int l0b = blockIdx.x * 64;
    int d0 = blockIdx.y * 64;
    int d = t & 63, lg = t >> 6;
    int col = d0 + d;
    int l0 = l0b + lg * 16;

    float c00 = w_conv[col * 3 + 0], c01 = w_conv[col * 3 + 1], c02 = w_conv[col * 3 + 2];
    float bc0 = b_conv[col];
    int e2 = 2048 + col;
    float c20 = w_conv[e2 * 3 + 0], c21 = w_conv[e2 * 3 + 1], c22 = w_conv[e2 * 3 + 2];
    float bc2 = b_conv[e2];

    size_t base = ((size_t)b * 4096 + l0) * 1024 + col;
    float p01 = (l0 >= 1) ? (float)u0[base - 1024] : 0.f;
    float p02 = (l0 >= 2) ? (float)u0[base - 2048] : 0.f;
    float p21 = (l0 >= 1) ? (float)u2[base - 1024] : 0.f;
    float p22 = (l0 >= 2) ? (float)u2[base - 2048] : 0.f;
    #pragma unroll
    for (int il = 0; il < 16; ++il) {
        float c0v = (float)u0[base + (size_t)il * 1024];
        float c2v = (float)u2[base + (size_t)il * 1024];
        float s0v = c00 * p02 + c01 * p01 + c02 * c0v + bc0;
        float s2v = c20 * p22 + c21 * p21 + c22 * c2v + bc2;
        p02 = p01; p01 = c0v; p22 = p21; p21 = c2v;
        vt[lg * 16 + il][d] = s0v * s2v;
        st[base + (size_t)il * 1024] = (__bf16)s0v;   // [B,L,D] direct, coalesced
    }
    __syncthreads();
    int lo = t & 63, dg = t >> 6;
    size_t obase = ((size_t)b * 1024 + d0 + dg * 16) * 4096 + l0b + lo;
    #pragma unroll
    for (int id = 0; id < 16; ++id)
        v[obase + (size_t)id * 4096] = (__bf16)vt[lo][dg * 16 + id];
}

// ---------------- K3: 1024-tap causal FIR via MFMA block-Toeplitz -------------
__global__ __launch_bounds__(256) void firk(const __bf16* __restrict__ v,
                                            const __bf16* __restrict__ afg,
                                            const float* __restrict__ filt_bias,
                                            __bf16* __restrict__ z) {
    __shared__ __bf16 vlds[768 * 8];       // chunks 0..129 zero-pad, 130..641 data
    __shared__ __bf16 alds[33 * 64 * 8];   // A-fragments, lane-contiguous
    int t = threadIdx.x;
    int bd = blockIdx.x;          // b*1024 + d
    int d = bd & 1023;
    const __bf16* vrow = v + (size_t)bd * 4096;

    for (int c = t; c < 33 * 64; c += 256)
        *(bf16x8*)&alds[c * 8] = *(const bf16x8*)&afg[(size_t)c * 8];
    #pragma unroll
    for (int i = 0; i < 3; ++i) {
        int c = t + i * 256;
        bf16x8 val = {};
        if (c >= 130 && c < 642) val = *(const bf16x8*)&vrow[(c - 130) * 8];
        int cs = c ^ ((c >> 3) & 7);
        *(bf16x8*)&vlds[cs * 8] = val;
    }
    __syncthreads();

    int lane = t & 63, w = t >> 6;
    int n = lane & 15, kh = lane >> 4;
    int khoff = (kh == 0) ? 0 : (kh == 1) ? 8 : (kh == 2) ? -16 : -8;
    f32x4 acc[4] = {};
    for (int sp = 0; sp < 33; ++sp) {
        bf16x8 af = *(const bf16x8*)&alds[(sp * 64 + lane) * 8];
        #pragma unroll
        for (int ct = 0; ct < 4; ++ct) {
            int p = w * 64 + ct * 16 + n;
            int e = 16 * p - 32 * sp + 1040 + khoff;   // vpad index, multiple of 8
            int c = e >> 3;
            int cs = c ^ ((c >> 3) & 7);
            bf16x8 bfv = *(const bf16x8*)&vlds[cs * 8];
            acc[ct] = __builtin_amdgcn_mfma_f32_16x16x32_bf16(af, bfv, acc[ct], 0, 0, 0);
        }
    }

    float fb = filt_bias[d];
    __bf16* zrow = z + (size_t)bd * 4096;
    #pragma unroll
    for (int ct = 0; ct < 4; ++ct) {
        int p = w * 64 + ct * 16 + n;
        #pragma unroll
        for (int j = 0; j < 4; ++j) {
            int l = 16 * p + kh * 4 + j;
            int e = l + 1040;
            int c = e >> 3;
            int cs = c ^ ((c >> 3) & 7);
            float vv = (float)vlds[cs * 8 + (e & 7)];
            zrow[l] = (__bf16)(acc[ct][j] + vv * fb);
        }
    }
}

// ---------------- K3b: transpose zz [B,D,L] -> [B,L,D] and gate by s0 ---------
__global__ __launch_bounds__(256) void trz(const __bf16* __restrict__ zz,
                                           const __bf16* __restrict__ st,
                                           __bf16* __restrict__ zt) {
    __shared__ __bf16 tile[64][65];
    int t = threadIdx.x;
    int l0 = blockIdx.x * 64, d0 = blockIdx.y * 64, b = blockIdx.z;
    int c = t & 63, rg = t >> 6;
    #pragma unroll
    for (int i = 0; i < 16; ++i) {
        int r = rg * 16 + i;
        tile[r][c] = zz[((size_t)(b * 1024 + d0 + r)) * 4096 + l0 + c];
    }
    __syncthreads();
    #pragma unroll
    for (int i = 0; i < 16; ++i) {
        int li = rg * 16 + i;
        size_t o = ((size_t)b * 4096 + l0 + li) * 1024 + d0 + c;
        zt[o] = (__bf16)((float)tile[c][li] * (float)st[o]);
    }
}

extern "C" void kernel_launch(void* const* d_in, const int* in_sizes, int n_in,
                              void* d_out, int out_size, void* d_ws, size_t ws_size,
                              hipStream_t stream) {
    const float* x      = (const float*)d_in[0];
    const float* w_in   = (const float*)d_in[1];
    const float* b_in   = (const float*)d_in[2];
    const float* w_conv = (const float*)d_in[3];
    const float* b_conv = (const float*)d_in[4];
    // d_in[5] = w1: multiplied by t[0]==0, mathematically unused for h
    const float* b1     = (const float*)d_in[6];
    const float* w2     = (const float*)d_in[7];
    const float* b2     = (const float*)d_in[8];
    const float* w3     = (const float*)d_in[9];
    const float* fb     = (const float*)d_in[10];
    const float* w_out  = (const float*)d_in[11];
    const float* b_out  = (const float*)d_in[12];
    float* out = (float*)d_out;

    // Workspace span = 40960 + 64 MB (round-1-proven bound), temporally aliased:
    //   X : xbf (P1) -> vv (P2-P3) -> wot (P5)
    //   U0: u0  (P1-P2) -> zt (P4-P5)
    //   U2: u2  (P1-P2) -> zz (P3-P4)
    //   ST: st  (P2...) ; WT overlaps ST's tail (WT dead before st written)
    char* ws = (char*)d_ws;
    float*  h  = (float*)ws;                          // 4 KB
    __bf16* af = (__bf16*)(ws + 4096);                // 33 KB
    const size_t SEG = (size_t)8192 * 1024;
    __bf16* X  = (__bf16*)(ws + 40960);
    __bf16* U0 = X + SEG;
    __bf16* U2 = U0 + SEG;
    __bf16* ST = U2 + SEG;
    __bf16* WT = ST + SEG - (size_t)2048 * 1024;      // [2048][1024] bf16, 4 MB

    hgen<<<1, 256, 0, stream>>>(b1, w2, b2, w3, h);
    hfrag<<<33, 64, 0, stream>>>(h, af);
    cvt_x<<<4096, 256, 0, stream>>>(x, X);
    tcvt<<<dim3(16, 16), 256, 0, stream>>>(w_in, WT, 3072, 0);
    tcvt<<<dim3(16, 16), 256, 0, stream>>>(w_in, WT + (size_t)1024 * 1024, 3072, 2048);
    gemm256<<<dim3(32, 8), 512, 0, stream>>>(X, WT, b_in, U0, U2);
    convmul<<<dim3(64, 16, 2), 256, 0, stream>>>(U0, U2, w_conv, b_conv, X, ST);
    firk<<<2048, 256, 0, stream>>>(X, af, fb, U2);
    tcvt<<<dim3(16, 16), 256, 0, stream>>>(w_out, X, 1024, 0);   // wot into X (vv dead)
    trz<<<dim3(64, 16, 2), 256, 0, stream>>>(U2, ST, U0);
    gemm128<1><<<dim3(64, 8), 256, 0, stream>>>(U0, X, b_out, (void*)out, nullptr);
}